// Round 12
// baseline (1305.320 us; speedup 1.0000x reference)
//
#include <hip/hip_runtime.h>

#define S_TOT 65536
#define RANK  512
#define NG    6                      // G rows that matter: W[1..6]
#define ROWS_PER_BLK 256
#define CHUNKS (S_TOT / ROWS_PER_BLK)  // 256

// ---------------------------------------------------------------------------
// k1: G[n-1][r] += sum_s z[s] * W[n][s][r]   for n = 1..6
// grid = (CHUNKS, NG), block = 256.
// thread t: columns c4 = (t&127)*4 .. +3 (float4), row parity t>>7.
// z chunk staged in LDS (broadcast reads, no per-iter global latency).
// ---------------------------------------------------------------------------
__global__ __launch_bounds__(256) void k1_reduce(const float* __restrict__ z,
                                                 const float* __restrict__ W,
                                                 float* __restrict__ G) {
    const int chunk = blockIdx.x;
    const int n     = blockIdx.y + 1;          // W slice index 1..6
    const int t     = threadIdx.x;
    const int c4    = (t & 127) * 4;
    const int rp    = t >> 7;                  // 0 or 1

    const int  s0   = chunk * ROWS_PER_BLK;

    __shared__ float zs[ROWS_PER_BLK];
    zs[t] = z[s0 + t];
    __syncthreads();

    const long base = (long)n * S_TOT * RANK + (long)s0 * RANK;
    const float* Wp = W + base;

    float4 acc = make_float4(0.f, 0.f, 0.f, 0.f);

#pragma unroll 4
    for (int i = rp; i < ROWS_PER_BLK; i += 2) {
        const float  zz = zs[i];                                   // LDS broadcast
        const float4 w  = *(const float4*)(Wp + (long)i * RANK + c4);
        acc.x += zz * w.x;
        acc.y += zz * w.y;
        acc.z += zz * w.z;
        acc.w += zz * w.w;
    }

    __shared__ float4 lds[256];
    lds[t] = acc;
    __syncthreads();

    if (t < 128) {
        const float4 a = lds[t];
        const float4 c = lds[t + 128];
        float* g = G + (long)(n - 1) * RANK + c4;
        atomicAdd(g + 0, a.x + c.x);
        atomicAdd(g + 1, a.y + c.y);
        atomicAdd(g + 2, a.z + c.z);
        atomicAdd(g + 3, a.w + c.w);
    }
}

// ---------------------------------------------------------------------------
// k2: Ssum[r] = 2 + sum_{j=0..5} prod_{i<=j} G[i][r]
// one block, 512 threads
// ---------------------------------------------------------------------------
__global__ void k2_ssum(const float* __restrict__ G, float* __restrict__ Ssum) {
    const int r = threadIdx.x;
    float p = 1.f;
    float s = 2.f;
#pragma unroll
    for (int j = 0; j < NG; ++j) {
        p *= G[j * RANK + r];
        s += p;
    }
    Ssum[r] = s;
}

// ---------------------------------------------------------------------------
// k3: out[s] = dot(W[0][s][:], Ssum) + b[s]
// block = 256 (4 waves), one wave per output row; grid = S_TOT/4
// ---------------------------------------------------------------------------
__global__ __launch_bounds__(256) void k3_gemv(const float* __restrict__ W0,
                                               const float* __restrict__ Ssum,
                                               const float* __restrict__ b,
                                               float* __restrict__ out) {
    __shared__ float ss[RANK];
    const int t = threadIdx.x;
    ss[t]       = Ssum[t];
    ss[t + 256] = Ssum[t + 256];
    __syncthreads();

    const int wave = t >> 6;
    const int lane = t & 63;
    const int s    = blockIdx.x * 4 + wave;

    const float* row = W0 + (long)s * RANK;
    const float4 w0 = *(const float4*)(row + lane * 4);
    const float4 w1 = *(const float4*)(row + 256 + lane * 4);
    const float4 s0 = *(const float4*)(ss + lane * 4);
    const float4 s1 = *(const float4*)(ss + 256 + lane * 4);

    float acc = w0.x * s0.x + w0.y * s0.y + w0.z * s0.z + w0.w * s0.w
              + w1.x * s1.x + w1.y * s1.y + w1.z * s1.z + w1.w * s1.w;

#pragma unroll
    for (int off = 32; off; off >>= 1)
        acc += __shfl_down(acc, off, 64);

    if (lane == 0)
        out[s] = acc + b[s];
}

extern "C" void kernel_launch(void* const* d_in, const int* in_sizes, int n_in,
                              void* d_out, int out_size, void* d_ws, size_t ws_size,
                              hipStream_t stream) {
    const float* z = (const float*)d_in[0];
    const float* W = (const float*)d_in[1];
    const float* b = (const float*)d_in[2];
    float* out = (float*)d_out;

    float* G    = (float*)d_ws;          // NG*RANK floats
    float* Ssum = G + NG * RANK;         // RANK floats

    // ws is poisoned to 0xAA before every timed call — zero the accumulator.
    hipMemsetAsync(G, 0, NG * RANK * sizeof(float), stream);

    dim3 g1(CHUNKS, NG);
    k1_reduce<<<g1, 256, 0, stream>>>(z, W, G);
    k2_ssum<<<1, RANK, 0, stream>>>(G, Ssum);
    k3_gemv<<<S_TOT / 4, 256, 0, stream>>>(W, Ssum, b, out);
}